// Round 8
// baseline (184.541 us; speedup 1.0000x reference)
//
#include <hip/hip_runtime.h>
#include <math.h>

// ---------------------------------------------------------------------------
// ForceFieldPredictor R20 = R18 with n-split epilogue (4 barriers -> 3).
//   Evidence: R19 showed +3 barriers = +10.7us (~3.5us/barrier) and that
//   occupancy is NOT the lever (R14: 52% occ was slower than R12's 27%).
//   Limiter = per-block serial phase chain. R20 shortens it:
//   P4 is n-split: wave w handles ITS 16 queries (rows w*16+r of ACTB)
//   over ALL 128 neurons; afT2/afJ0 loaded transiently from L2 per mt
//   (~40KB/block extra L2, hidden under MFMA). Joint moved into P4 with
//   bJ built from registers (R15-verified construction) -> JINB deleted.
//   m-partials reduce within the wave (shfl_xor 16/32); lanes 0-15 store
//   directly -> fred, smf, P5, and the 4th barrier all deleted.
//   P1 computes epilogue scalars in ALL lanes (register-resident).
// Layouts (verified R3-R18): A[m=l&15][k=(l>>4)*8+j], B[k][n=l&15],
// C col=l&15(query), row=(l>>4)*4+reg(neuron).
// ---------------------------------------------------------------------------

typedef _Float16 h4v __attribute__((ext_vector_type(4)));
typedef _Float16 h8v __attribute__((ext_vector_type(8)));
typedef float    f4v __attribute__((ext_vector_type(4)));

#define AH 136

// ---- d_ws layout ----
#define TW0_OFF 0
#define JW0_OFF 4096
#define TWS_OFF 8192
#define BW0_OFF 40960
#define BWS_OFF 45056
#define W_TOTAL 77824      // halfs; brw (fp32) follows
#define BR_OFF_F (W_TOTAL/2)

// ---- ff LDS halfs ----
#define H_ACTA 0            // 64 x 136
#define H_ACTB 8704         // 64 x 136
#define H_TINB 17408        // 2048 halfs
#define SMH_SIZE 19456      // 38912 B -> 4 blk/CU

#define FRAG_BLOCKS 304
#define BR_BLOCKS   256

// ===========================================================================
__global__ __launch_bounds__(256)
void prep_kernel(const float* __restrict__ tw0, const float* __restrict__ tws,
                 const float* __restrict__ jw0, const float* __restrict__ bw0,
                 const float* __restrict__ bws, const float* __restrict__ bb0,
                 const float* __restrict__ bbs, const float* __restrict__ init_x,
                 _Float16* __restrict__ wsH, float* __restrict__ brw)
{
    __shared__ float bsm[2*16*132];       // branch path only (16896 B)
    const int tid = threadIdx.x;

    if (blockIdx.x < FRAG_BLOCKS) {
        int idx = blockIdx.x * 256 + tid;
        if (idx >= W_TOTAL) return;
        const int j = idx & 7;
        const int lane = (idx >> 3) & 63;
        const int q = lane >> 4, r = lane & 15;
        _Float16 v;
        if (idx < JW0_OFF) {                       // trunk w0 (K 9, pad 32)
            int mt = idx >> 9;
            int k = q*8 + j, m = mt*16 + r;
            v = (k < 9) ? (_Float16)tw0[k*128 + m] : (_Float16)0.f;
        } else if (idx < TWS_OFF) {                // joint w0 (K 15, pad 32)
            int mt = (idx - JW0_OFF) >> 9;
            int k = q*8 + j, m = mt*16 + r;
            v = (k < 15) ? (_Float16)jw0[k*128 + m] : (_Float16)0.f;
        } else if (idx < BW0_OFF) {                // trunk ws[0..1]
            int e = idx - TWS_OFF;
            int ks = (e >> 9) & 3, mt = (e >> 11) & 7, l = e >> 14;
            int k = ks*32 + q*8 + j, m = mt*16 + r;
            v = (_Float16)tws[l*16384 + k*128 + m];
        } else if (idx < BWS_OFF) {                // branch w0 (pad)
            int mt = (idx - BW0_OFF) >> 9;
            int k = q*8 + j, m = mt*16 + r;
            v = (k < 5) ? (_Float16)bw0[k*128 + m] : (_Float16)0.f;
        } else {                                   // branch ws[0..1]
            int e = idx - BWS_OFF;
            int ks = (e >> 9) & 3, mt = (e >> 11) & 7, l = e >> 14;
            int k = ks*32 + q*8 + j, m = mt*16 + r;
            v = (_Float16)bws[l*16384 + k*128 + m];
        }
        wsH[idx] = v;
        return;
    }

    // ---- branch MLP: 16 rows per block ------------------------------------
    const int blk2 = blockIdx.x - FRAG_BLOCKS;
    const int row0 = blk2*16;
    const int lane = tid & 63, w = tid >> 6;
    const int q = lane >> 4, r = lane & 15;
    float* h0 = bsm;
    float* h1 = bsm + 16*132;

    for (int e = tid; e < 2048; e += 256) {
        const int rw = e >> 7, n = e & 127;
        const float* ixp = init_x + (row0 + rw)*9;
        float acc = bb0[n];
        acc = fmaf(ixp[2], bw0[2*128 + n], acc);
        acc = fmaf(ixp[3], bw0[3*128 + n], acc);
        acc = fmaf(ixp[4], bw0[4*128 + n], acc);
        h0[rw*132 + n] = acc;
    }
    __syncthreads();

    #pragma unroll
    for (int L = 0; L < 2; ++L) {
        const float* Wg = bws + L*16384;
        const float* bi = bbs + L*128;
        const float* in = (L == 0) ? h0 : h1;
        #pragma unroll
        for (int mi = 0; mi < 2; ++mi) {
            const int mt = w + mi*4;
            const int m0 = mt*16 + q*4;
            h8v af[4];
            #pragma unroll
            for (int ks = 0; ks < 4; ++ks)
                #pragma unroll
                for (int j = 0; j < 8; ++j)
                    af[ks][j] = (_Float16)Wg[(ks*32 + q*8 + j)*128 + mt*16 + r];
            f4v acc = *(const f4v*)&bi[m0];
            #pragma unroll
            for (int ks = 0; ks < 4; ++ks) {
                f4v x0 = *(const f4v*)&in[r*132 + ks*32 + q*8];
                f4v x1 = *(const f4v*)&in[r*132 + ks*32 + q*8 + 4];
                h8v bf;
                #pragma unroll
                for (int i = 0; i < 4; ++i) {
                    bf[i]   = (_Float16)fmaxf(x0[i], 0.f);
                    bf[4+i] = (_Float16)fmaxf(x1[i], 0.f);
                }
                acc = __builtin_amdgcn_mfma_f32_16x16x32_f16(af[ks], bf, acc, 0, 0, 0);
            }
            if (L == 0)
                *(f4v*)&h1[r*132 + m0] = acc;
            else
                *(f4v*)&brw[(row0 + r)*128 + m0] = acc;
        }
        __syncthreads();
    }
}

// ===========================================================================
__device__ __forceinline__ void layerK32_rw(const h8v af[2],
        const float* __restrict__ bias, const _Float16* __restrict__ inB,
        _Float16* __restrict__ actOut, int lane, int w)
{
    const int q = lane >> 4, r = lane & 15;
    #pragma unroll
    for (int nt = 0; nt < 4; ++nt) {
        h8v bf = *(const h8v*)&inB[(nt*64 + lane)*8];
        #pragma unroll
        for (int mi = 0; mi < 2; ++mi) {
            f4v acc = *(const f4v*)&bias[(2*w + mi)*16 + q*4];
            acc = __builtin_amdgcn_mfma_f32_16x16x32_f16(af[mi], bf, acc, 0, 0, 0);
            h4v o;
            #pragma unroll
            for (int i = 0; i < 4; ++i) o[i] = (_Float16)fmaxf(acc[i], 0.f);
            *(h4v*)&actOut[(nt*16 + r)*AH + (2*w + mi)*16 + q*4] = o;
        }
    }
}

__device__ __forceinline__ void layerK128_rw(const h8v af[2][4],
        const float* __restrict__ bias, const _Float16* __restrict__ actIn,
        _Float16* __restrict__ actOut, int lane, int w)
{
    const int q = lane >> 4, r = lane & 15;
    #pragma unroll
    for (int nt = 0; nt < 4; ++nt) {
        h8v bf[4];
        #pragma unroll
        for (int ks = 0; ks < 4; ++ks)
            bf[ks] = *(const h8v*)&actIn[(nt*16 + r)*AH + ks*32 + q*8];
        #pragma unroll
        for (int mi = 0; mi < 2; ++mi) {
            f4v acc = *(const f4v*)&bias[(2*w + mi)*16 + q*4];
            #pragma unroll
            for (int ks = 0; ks < 4; ++ks)
                acc = __builtin_amdgcn_mfma_f32_16x16x32_f16(af[mi][ks], bf[ks], acc, 0, 0, 0);
            h4v o;
            #pragma unroll
            for (int i = 0; i < 4; ++i) o[i] = (_Float16)fmaxf(acc[i], 0.f);
            *(h4v*)&actOut[(nt*16 + r)*AH + (2*w + mi)*16 + q*4] = o;
        }
    }
}

// ===========================================================================
__global__ __launch_bounds__(256, 3)
void ff_kernel(const float* __restrict__ init_x,  const float* __restrict__ query_x,
               const float* __restrict__ init_v,  const float* __restrict__ query_v,
               const float* __restrict__ init_av, const float* __restrict__ query_av,
               const float* __restrict__ tb0, const float* __restrict__ tbs,
               const float* __restrict__ out_w, const float* __restrict__ out_b,
               const float* __restrict__ sw0, const float* __restrict__ sb0,
               const float* __restrict__ sw1, const float* __restrict__ sb1,
               const float* __restrict__ jb0,
               const float* __restrict__ jw1, const float* __restrict__ jb1,
               const _Float16* __restrict__ wsH, const float* __restrict__ brw,
               float* __restrict__ out)
{
    __shared__ __align__(16) _Float16 smh[SMH_SIZE];
    const int tid = threadIdx.x;
    const int bid = blockIdx.x;
    const int o  = bid & 63;
    const int b  = bid >> 6;
    const int lane = tid & 63, w = tid >> 6;
    const int q = lane >> 4, r = lane & 15;
    const float* ix = init_x + (b*64 + o)*9;

    // ---- P0: hold only L0/L1 A-frags (40 VGPR) -----------------------------
    h8v afT0[2], afT1[2][4];
    #pragma unroll
    for (int mi = 0; mi < 2; ++mi) {
        const int mtg = 2*w + mi;
        afT0[mi] = *(const h8v*)&wsH[TW0_OFF + (mtg*64 + lane)*8];
        #pragma unroll
        for (int ks = 0; ks < 4; ++ks)
            afT1[mi][ks] = *(const h8v*)&wsH[TWS_OFF + ((mtg*4 + ks)*64 + lane)*8];
    }

    // ---- P1: geometry; epilogue scalars in ALL lanes; bT/bJ in registers ---
    float maskS, dvxS, dvyS, hsS, hjS, lenS;
    h8v bT, bJ;
    {
        const int tq = w*16 + r;
        const float* qx = query_x + (b*64 + tq)*9;
        const float ix0 = ix[0], ix1 = ix[1], ix2 = ix[2], ix3 = ix[3], ix4 = ix[4];
        const float ix7 = ix[7], ix8 = ix[8];
        const float qx0 = qx[0], qx1 = qx[1], qx2 = qx[2], qx3 = qx[3], qx4 = qx[4];
        const float qx7 = qx[7], qx8 = qx[8];
        const float rel0 = qx0 - ix0, rel1 = qx1 - ix1;

        float s1v, c1v; sincosf(ix3 * 100.f, &s1v, &c1v);
        float s2v, c2v; sincosf(qx3 * 100.f, &s2v, &c2v);
        const float h1 = ix2 * 0.5f, h2 = qx2 * 0.5f;
        const float o1x = h1*c1v, o1y = h1*s1v;
        const float o2x = h2*c2v, o2y = h2*s2v;
        const float A1x = -o1x, A1y = -o1y;
        const float A2x = rel0 - o2x, A2y = rel1 - o2y;
        const float B2x = rel0 + o2x, B2y = rel1 + o2y;
        const float ab1x = 2.f*o1x, ab1y = 2.f*o1y;
        const float ab2x = 2.f*o2x, ab2y = 2.f*o2y;
        const float s1sq = ab1x*ab1x + ab1y*ab1y + 1e-8f;
        const float s2sq = ab2x*ab2x + ab2y*ab2y + 1e-8f;

        float Px, Py, Ax, Ay, ABx, ABy, ss;
        if (q < 2) {
            Ax = A1x; Ay = A1y; ABx = ab1x; ABy = ab1y; ss = s1sq;
            Px = (q == 0) ? A2x : B2x;  Py = (q == 0) ? A2y : B2y;
        } else {
            Ax = A2x; Ay = A2y; ABx = ab2x; ABy = ab2y; ss = s2sq;
            Px = (q == 2) ? A1x : o1x;  Py = (q == 2) ? A1y : o1y;
        }
        float t = ((Px - Ax)*ABx + (Py - Ay)*ABy) / ss;
        t = fminf(fmaxf(t, 0.f), 1.f);
        const float dx = Px - (Ax + t*ABx);
        const float dy = Py - (Ay + t*ABy);
        float dq = sqrtf(dx*dx + dy*dy);
        dq = fminf(dq, __shfl_xor(dq, 16));
        dq = fminf(dq, __shfl_xor(dq, 32));

        const float dist = dq - ix4 - qx4;
        const float mask = (dist <= 0.f) ? 1.f : 0.f;
        const float dinp = dist * mask * 100.f;
        const float qv0 = query_v[(b*64+tq)*2+0] - init_v[(b*64+o)*2+0];
        const float qv1 = query_v[(b*64+tq)*2+1] - init_v[(b*64+o)*2+1];
        const float iav = init_av[b*64+o];
        const float qav = query_av[b*64+tq] - iav;
        const float len = sqrtf(rel0*rel0 + rel1*rel1);
        const float inv = 1.f / (len + 1e-8f);
        const float i7t = truncf(ix7);
        const float fr7 = ix7 - i7t;

        maskS = mask;
        dvxS  = -rel0 * inv;
        dvyS  = -rel1 * inv;
        hsS   = ((ix8 == qx8) && (ix8 > 0.f)) ? 1.f : 0.f;
        hjS   = ((i7t == truncf(qx7)) && (ix7 > 0.f)) ? 1.f : 0.f;
        lenS  = len;

        // bT/bJ B-frags from registers (R15-verified): elem j = feature q*8+j
        const bool g0 = (q == 0), g1 = (q == 1);
        bT[0] = (_Float16)(g0 ? rel0 : g1 ? dinp : 0.f);
        bT[1] = (_Float16)(g0 ? rel1 : 0.f);
        bT[2] = (_Float16)(g0 ? qx2  : 0.f);
        bT[3] = (_Float16)(g0 ? qx3  : 0.f);
        bT[4] = (_Float16)(g0 ? qx4  : 0.f);
        bT[5] = (_Float16)(g0 ? qv0  : 0.f);
        bT[6] = (_Float16)(g0 ? qv1  : 0.f);
        bT[7] = (_Float16)(g0 ? qav  : 0.f);
        bJ[0] = (_Float16)(g1 ? qx3  : 0.f);
        bJ[1] = (_Float16)(g1 ? qx4  : 0.f);
        bJ[2] = (_Float16)(g0 ? ix2  : g1 ? qv0 : 0.f);
        bJ[3] = (_Float16)(g0 ? ix3  : g1 ? qv1 : 0.f);
        bJ[4] = (_Float16)(g0 ? ix4  : g1 ? iav : 0.f);
        bJ[5] = (_Float16)(g0 ? rel0 : g1 ? qav : 0.f);
        bJ[6] = (_Float16)(g0 ? rel1 : g1 ? fr7 : 0.f);
        bJ[7] = (_Float16)(g0 ? qx2  : 0.f);

        if (q == 0) {                     // TINB staging (cross-wave, for L0)
            const int fb = w*512 + r*8;
            h8v t0, t1 = {}, z = {};
            t0[0]=(_Float16)rel0; t0[1]=(_Float16)rel1; t0[2]=(_Float16)qx2;
            t0[3]=(_Float16)qx3;  t0[4]=(_Float16)qx4;  t0[5]=(_Float16)qv0;
            t0[6]=(_Float16)qv1;  t0[7]=(_Float16)qav;
            t1[0]=(_Float16)dinp;
            *(h8v*)&smh[H_TINB + fb]       = t0;
            *(h8v*)&smh[H_TINB + fb + 128] = t1;
            *(h8v*)&smh[H_TINB + fb + 256] = z;
            *(h8v*)&smh[H_TINB + fb + 384] = z;
        }
    }
    __syncthreads();

    // ---- P2: trunk L0 (m-split) --------------------------------------------
    layerK32_rw(afT0, tb0, smh + H_TINB, smh + H_ACTA, lane, w);
    __syncthreads();

    // ---- P3: trunk L1 (m-split, ACTA -> ACTB) ------------------------------
    layerK128_rw(afT1, tbs, smh + H_ACTA, smh + H_ACTB, lane, w);
    __syncthreads();

    // ---- P4: n-split epilogue: joint + L2 + folds, wave-local --------------
    // Wave w owns queries w*16+c (c=lane&15): reads ACTB rows it needs,
    // loads afJ0/afT2 transiently from L2, folds over all 128 neurons,
    // reduces over q-groups in-wave, stores. No fred/P5/barrier.
    h8v bf[4];
    #pragma unroll
    for (int ks = 0; ks < 4; ++ks)
        bf[ks] = *(const h8v*)&smh[H_ACTB + (w*16 + r)*AH + ks*32 + q*8];

    float jf0 = 0.f, jf1 = 0.f, f0 = 0.f, f1 = 0.f, f2 = 0.f, sp = 0.f;
    #pragma unroll 2
    for (int mt = 0; mt < 8; ++mt) {
        const int m0 = mt*16 + q*4;
        // joint MFMA + fold
        h8v aJ = *(const h8v*)&wsH[JW0_OFF + (mt*64 + lane)*8];
        f4v accJ = *(const f4v*)&jb0[m0];
        accJ = __builtin_amdgcn_mfma_f32_16x16x32_f16(aJ, bJ, accJ, 0, 0, 0);
        f4v jwa = *(const f4v*)&jw1[m0*2];
        f4v jwb = *(const f4v*)&jw1[m0*2 + 4];
        {
            const float h0r = fmaxf(accJ[0], 0.f), h1r = fmaxf(accJ[1], 0.f);
            const float h2r = fmaxf(accJ[2], 0.f), h3r = fmaxf(accJ[3], 0.f);
            jf0 = fmaf(h0r, jwa[0], fmaf(h1r, jwa[2], fmaf(h2r, jwb[0], fmaf(h3r, jwb[2], jf0))));
            jf1 = fmaf(h0r, jwa[1], fmaf(h1r, jwa[3], fmaf(h2r, jwb[1], fmaf(h3r, jwb[3], jf1))));
        }
        // trunk L2 MFMA (transient A-frags)
        f4v acc = *(const f4v*)&tbs[128 + m0];
        #pragma unroll
        for (int ks = 0; ks < 4; ++ks) {
            h8v a2 = *(const h8v*)&wsH[TWS_OFF + 16384 + ((mt*4 + ks)*64 + lane)*8];
            acc = __builtin_amdgcn_mfma_f32_16x16x32_f16(a2, bf[ks], acc, 0, 0, 0);
        }
        // branch * trunk @ out_w fold
        f4v brv = *(const f4v*)&brw[bid*128 + m0];
        f4v oa = *(const f4v*)&out_w[m0*3];
        f4v ob = *(const f4v*)&out_w[m0*3 + 4];
        f4v oc = *(const f4v*)&out_w[m0*3 + 8];
        const float p0 = acc[0]*brv[0], p1 = acc[1]*brv[1];
        const float p2 = acc[2]*brv[2], p3 = acc[3]*brv[3];
        f0 += p0*oa[0] + p1*oa[3] + p2*ob[2] + p3*oc[1];
        f1 += p0*oa[1] + p1*ob[0] + p2*ob[3] + p3*oc[2];
        f2 += p0*oa[2] + p1*ob[1] + p2*oc[0] + p3*oc[3];
        // spring fold
        f4v w0v = *(const f4v*)&sw0[m0];
        f4v b0v = *(const f4v*)&sb0[m0];
        f4v w1v = *(const f4v*)&sw1[m0];
        #pragma unroll
        for (int i = 0; i < 4; ++i)
            sp = fmaf(fmaxf(fmaf(lenS, w0v[i], b0v[i]), 0.f), w1v[i], sp);
    }

    // ---- reduce over q-groups + store (wave-local, no barrier) -------------
    f0  += __shfl_xor(f0, 16);  f0  += __shfl_xor(f0, 32);
    f1  += __shfl_xor(f1, 16);  f1  += __shfl_xor(f1, 32);
    f2  += __shfl_xor(f2, 16);  f2  += __shfl_xor(f2, 32);
    jf0 += __shfl_xor(jf0, 16); jf0 += __shfl_xor(jf0, 32);
    jf1 += __shfl_xor(jf1, 16); jf1 += __shfl_xor(jf1, 32);
    sp  += __shfl_xor(sp, 16);  sp  += __shfl_xor(sp, 32);
    if (q == 0) {
        const float sf = (sp + sb1[0]) * hsS;
        const float j0 = (jf0 + jb1[0]) * hjS;
        const float j1 = (jf1 + jb1[1]) * hjS;
        float* op = out + ((bid*64) + w*16 + r)*3;
        op[0] = (f0 + out_b[0])*maskS + sf*dvxS + j0;
        op[1] = (f1 + out_b[1])*maskS + sf*dvyS + j1;
        op[2] = (f2 + out_b[2])*maskS;
    }
}

// ===========================================================================
extern "C" void kernel_launch(void* const* d_in, const int* in_sizes, int n_in,
                              void* d_out, int out_size, void* d_ws, size_t ws_size,
                              hipStream_t stream) {
    (void)in_sizes; (void)n_in; (void)out_size; (void)ws_size;
    _Float16* wsH = (_Float16*)d_ws;
    float* brw = (float*)d_ws + BR_OFF_F;

    prep_kernel<<<dim3(FRAG_BLOCKS + BR_BLOCKS), dim3(256), 0, stream>>>(
        (const float*)d_in[6],   // trunk_w0
        (const float*)d_in[8],   // trunk_ws
        (const float*)d_in[20],  // joint_w0
        (const float*)d_in[10],  // branch_w0
        (const float*)d_in[12],  // branch_ws
        (const float*)d_in[11],  // branch_b0
        (const float*)d_in[13],  // branch_bs
        (const float*)d_in[0],   // init_x
        wsH, brw);
    ff_kernel<<<dim3(64*64), dim3(256), 0, stream>>>(
        (const float*)d_in[0],  (const float*)d_in[1],  (const float*)d_in[2],
        (const float*)d_in[3],  (const float*)d_in[4],  (const float*)d_in[5],
        (const float*)d_in[7],  (const float*)d_in[9],                  // tb0, tbs
        (const float*)d_in[14], (const float*)d_in[15],                 // out_w, out_b
        (const float*)d_in[16], (const float*)d_in[17],                 // sw0, sb0
        (const float*)d_in[18], (const float*)d_in[19],                 // sw1, sb1
        (const float*)d_in[21],                                         // jb0
        (const float*)d_in[22], (const float*)d_in[23],                 // jw1, jb1
        wsH, brw, (float*)d_out);
}